// Round 1
// baseline (33.775 us; speedup 1.0000x reference)
//
#include <hip/hip_runtime.h>
#include <hip/hip_bf16.h>

// MeanSpanRepr: out[q, :] = mean over t in [start[q], end[q]] of x[batch[q], t, :]
// B=32, T=512, D=256, Q=2048. x: float32 [B,T,D]; ids: int32 [Q]; out: float32 [Q,D].

constexpr int kT = 512;
constexpr int kD = 256;
constexpr int kD4 = kD / 4;   // 64 float4 chunks per row

__global__ __launch_bounds__(256) void span_mean_kernel(
    const float* __restrict__ x,
    const int* __restrict__ start_ids,
    const int* __restrict__ end_ids,
    const int* __restrict__ batch_ids,
    float* __restrict__ out) {
    const int q   = blockIdx.x;
    const int tid = threadIdx.x;
    const int c   = tid & 63;   // float4 chunk index within a row [0,64)
    const int tr  = tid >> 6;   // t-group [0,4)

    const int st = start_ids[q];
    const int en = end_ids[q];
    const int b  = batch_ids[q];
    const int len = en - st + 1;

    const float4* __restrict__ row_base =
        reinterpret_cast<const float4*>(x + (size_t)b * kT * kD) + c;

    float4 acc = make_float4(0.f, 0.f, 0.f, 0.f);
    for (int t = st + tr; t <= en; t += 4) {
        float4 v = row_base[(size_t)t * kD4];
        acc.x += v.x; acc.y += v.y; acc.z += v.z; acc.w += v.w;
    }

    __shared__ float4 red[256];
    red[tid] = acc;
    __syncthreads();

    if (tr == 0) {
        float4 a0 = red[c];
        float4 a1 = red[64 + c];
        float4 a2 = red[128 + c];
        float4 a3 = red[192 + c];
        const float inv = 1.0f / (float)len;
        float4 r;
        r.x = (a0.x + a1.x + a2.x + a3.x) * inv;
        r.y = (a0.y + a1.y + a2.y + a3.y) * inv;
        r.z = (a0.z + a1.z + a2.z + a3.z) * inv;
        r.w = (a0.w + a1.w + a2.w + a3.w) * inv;
        reinterpret_cast<float4*>(out)[(size_t)q * kD4 + c] = r;
    }
}

extern "C" void kernel_launch(void* const* d_in, const int* in_sizes, int n_in,
                              void* d_out, int out_size, void* d_ws, size_t ws_size,
                              hipStream_t stream) {
    const float* x        = (const float*)d_in[0];
    const int* start_ids  = (const int*)d_in[1];
    const int* end_ids    = (const int*)d_in[2];
    const int* batch_ids  = (const int*)d_in[3];
    float* out            = (float*)d_out;

    const int Q = in_sizes[1];  // 2048
    span_mean_kernel<<<Q, 256, 0, stream>>>(x, start_ids, end_ids, batch_ids, out);
}

// Round 2
// 17.269 us; speedup vs baseline: 1.9558x; 1.9558x over previous
//
#include <hip/hip_runtime.h>
#include <hip/hip_bf16.h>

// MeanSpanRepr via prefix sums.
// out[q,:] = (S[b, end, :] - S[b, start-1, :]) / len, where S is the
// cumulative sum of x[b, :, :] along t. S is stored as chunk-local prefixes
// plus per-chunk exclusive offsets (avoids a cross-chunk dependency pass).
// B=32, T=512, D=256, Q=2048.

constexpr int kB  = 32;
constexpr int kT  = 512;
constexpr int kD  = 256;
constexpr int kD4 = kD / 4;     // 64
constexpr int kCL = 32;         // chunk length (t)
constexpr int kNC = kT / kCL;   // 16 chunks

// ---------- kernel A: chunk-local inclusive scan along t ----------
__global__ __launch_bounds__(256) void scan_chunk_kernel(
    const float* __restrict__ x, float* __restrict__ S, float* __restrict__ Tot) {
    const int blk = blockIdx.x;        // b*kNC + chunk
    const int b = blk >> 4;            // / kNC
    const int c = blk & (kNC - 1);
    const int d = threadIdx.x;         // [0,256)

    const size_t rowbase = ((size_t)b * kT + (size_t)c * kCL) * kD + d;
    const float* __restrict__ px = x + rowbase;
    float* __restrict__ pS = S + rowbase;

    float acc = 0.f;
#pragma unroll
    for (int t = 0; t < kCL; ++t) {
        acc += px[(size_t)t * kD];
        pS[(size_t)t * kD] = acc;
    }
    Tot[((size_t)b * kNC + c) * kD + d] = acc;
}

// ---------- kernel B: exclusive scan of chunk totals ----------
__global__ __launch_bounds__(256) void scan_offsets_kernel(
    const float* __restrict__ Tot, float* __restrict__ Off) {
    const int b = blockIdx.x;
    const int d = threadIdx.x;
    float acc = 0.f;
#pragma unroll
    for (int c = 0; c < kNC; ++c) {
        const size_t i = ((size_t)b * kNC + c) * kD + d;
        Off[i] = acc;
        acc += Tot[i];
    }
}

// ---------- kernel C: per-query span mean from prefixes ----------
__global__ __launch_bounds__(256) void span_from_prefix_kernel(
    const float4* __restrict__ S4, const float4* __restrict__ Off4,
    const int* __restrict__ start_ids, const int* __restrict__ end_ids,
    const int* __restrict__ batch_ids, float4* __restrict__ out4, int Q) {
    const int q = blockIdx.x * 4 + (threadIdx.x >> 6);  // one wave per query
    if (q >= Q) return;
    const int lane = threadIdx.x & 63;

    const int s = start_ids[q];
    const int e = end_ids[q];
    const int b = batch_ids[q];

    const size_t sbase = (size_t)b * kT * kD4 + lane;
    const size_t obase = (size_t)b * kNC * kD4 + lane;

    float4 hi = S4[sbase + (size_t)e * kD4];
    float4 ho = Off4[obase + (size_t)(e >> 5) * kD4];
    float sx = hi.x + ho.x, sy = hi.y + ho.y, sz = hi.z + ho.z, sw = hi.w + ho.w;

    if (s > 0) {
        const int p = s - 1;
        float4 lo = S4[sbase + (size_t)p * kD4];
        float4 oo = Off4[obase + (size_t)(p >> 5) * kD4];
        sx -= lo.x + oo.x; sy -= lo.y + oo.y; sz -= lo.z + oo.z; sw -= lo.w + oo.w;
    }

    const float inv = 1.0f / (float)(e - s + 1);
    float4 r;
    r.x = sx * inv; r.y = sy * inv; r.z = sz * inv; r.w = sw * inv;
    out4[(size_t)q * kD4 + lane] = r;
}

// ---------- fallback: direct gather (round-1 kernel) ----------
__global__ __launch_bounds__(256) void span_mean_direct_kernel(
    const float* __restrict__ x,
    const int* __restrict__ start_ids, const int* __restrict__ end_ids,
    const int* __restrict__ batch_ids, float* __restrict__ out) {
    const int q   = blockIdx.x;
    const int tid = threadIdx.x;
    const int c   = tid & 63;
    const int tr  = tid >> 6;

    const int st = start_ids[q];
    const int en = end_ids[q];
    const int b  = batch_ids[q];
    const int len = en - st + 1;

    const float4* __restrict__ row_base =
        reinterpret_cast<const float4*>(x + (size_t)b * kT * kD) + c;

    float4 acc = make_float4(0.f, 0.f, 0.f, 0.f);
    for (int t = st + tr; t <= en; t += 4) {
        float4 v = row_base[(size_t)t * kD4];
        acc.x += v.x; acc.y += v.y; acc.z += v.z; acc.w += v.w;
    }

    __shared__ float4 red[256];
    red[tid] = acc;
    __syncthreads();

    if (tr == 0) {
        float4 a0 = red[c], a1 = red[64 + c], a2 = red[128 + c], a3 = red[192 + c];
        const float inv = 1.0f / (float)len;
        float4 r;
        r.x = (a0.x + a1.x + a2.x + a3.x) * inv;
        r.y = (a0.y + a1.y + a2.y + a3.y) * inv;
        r.z = (a0.z + a1.z + a2.z + a3.z) * inv;
        r.w = (a0.w + a1.w + a2.w + a3.w) * inv;
        reinterpret_cast<float4*>(out)[(size_t)q * kD4 + c] = r;
    }
}

extern "C" void kernel_launch(void* const* d_in, const int* in_sizes, int n_in,
                              void* d_out, int out_size, void* d_ws, size_t ws_size,
                              hipStream_t stream) {
    const float* x        = (const float*)d_in[0];
    const int* start_ids  = (const int*)d_in[1];
    const int* end_ids    = (const int*)d_in[2];
    const int* batch_ids  = (const int*)d_in[3];
    float* out            = (float*)d_out;
    const int Q = in_sizes[1];  // 2048

    const size_t bytesS   = (size_t)kB * kT * kD * sizeof(float);   // 16 MB
    const size_t bytesTot = (size_t)kB * kNC * kD * sizeof(float);  // 512 KB
    const size_t need     = bytesS + 2 * bytesTot;

    if (ws_size < need) {
        // workspace too small: direct gather fallback (correct, ~34 us)
        span_mean_direct_kernel<<<Q, 256, 0, stream>>>(x, start_ids, end_ids, batch_ids, out);
        return;
    }

    float* S   = (float*)d_ws;
    float* Tot = (float*)((char*)d_ws + bytesS);
    float* Off = (float*)((char*)d_ws + bytesS + bytesTot);

    scan_chunk_kernel<<<kB * kNC, 256, 0, stream>>>(x, S, Tot);
    scan_offsets_kernel<<<kB, 256, 0, stream>>>(Tot, Off);
    span_from_prefix_kernel<<<(Q + 3) / 4, 256, 0, stream>>>(
        (const float4*)S, (const float4*)Off, start_ids, end_ids, batch_ids,
        (float4*)out, Q);
}